// Round 1
// baseline (949.149 us; speedup 1.0000x reference)
//
#include <hip/hip_runtime.h>
#include <math.h>

#define BB 1024
#define SS 200
#define HH 128
#define NI 100000

__global__ __launch_bounds__(256, 2)
void rrd_fused_kernel(const float* __restrict__ allm,      // [B,S,H]
                      const float* __restrict__ lastm,     // [B,H]
                      const int* __restrict__ item_seq,    // [B,S]
                      const unsigned char* __restrict__ mask, // [B,S] bool
                      const float* __restrict__ Ur,        // [H,H]
                      const float* __restrict__ Wr,        // [H,H]
                      const float* __restrict__ Vr,        // [1,H]
                      const float* __restrict__ Vrb,       // [1]
                      float* __restrict__ out) {           // [B,N]
    const int b = blockIdx.x;
    const int tid = threadIdx.x;
    const int lane = tid & 63;
    const int wv = tid >> 6;

    // ---- 1. zero this batch's output row (N = 25000 float4 exactly) ----
    float4* orow = reinterpret_cast<float4*>(out + (size_t)b * NI);
    const float4 z4 = make_float4(0.f, 0.f, 0.f, 0.f);
    for (int i = tid; i < NI / 4; i += 256) orow[i] = z4;

    __shared__ float s_last[HH];
    __shared__ float s_lm[HH];
    __shared__ float s_red[8];

    // ---- 2. lm[k] = sum_h last[b,h] * Wr[k,h] ----
    if (tid < HH) s_last[tid] = lastm[b * HH + tid];
    __syncthreads();
    if (tid < HH) {
        const float* wrow = Wr + tid * HH;
        float a0 = 0.f, a1 = 0.f, a2 = 0.f, a3 = 0.f;
        #pragma unroll
        for (int h = 0; h < HH; h += 4) {
            a0 += s_last[h]     * wrow[h];
            a1 += s_last[h + 1] * wrow[h + 1];
            a2 += s_last[h + 2] * wrow[h + 2];
            a3 += s_last[h + 3] * wrow[h + 3];
        }
        s_lm[tid] = (a0 + a1) + (a2 + a3);
    }
    __syncthreads();

    // ---- 3. load this thread's A row into registers ----
    const int s = tid;  // one s per thread; lanes with s >= S are idle helpers
    float a[HH];
    {
        const float4* arow = reinterpret_cast<const float4*>(
            allm + ((size_t)b * SS + (s < SS ? s : 0)) * HH);
        #pragma unroll
        for (int i = 0; i < HH / 4; ++i) {
            float4 v = arow[i];
            a[4 * i]     = v.x;
            a[4 * i + 1] = v.y;
            a[4 * i + 2] = v.z;
            a[4 * i + 3] = v.w;
        }
    }

    // ---- 4. score[s] = Vrb + sum_k Vr[k] * tanh(am[s,k] + lm[k]) ----
    float score = Vrb[0];
    for (int k = 0; k < HH; ++k) {
        const float* urow = Ur + k * HH;   // k is uniform -> scalar loads
        float am0 = 0.f, am1 = 0.f, am2 = 0.f, am3 = 0.f;
        #pragma unroll
        for (int h = 0; h < HH; h += 4) {
            am0 += a[h]     * urow[h];
            am1 += a[h + 1] * urow[h + 1];
            am2 += a[h + 2] * urow[h + 2];
            am3 += a[h + 3] * urow[h + 3];
        }
        float am = (am0 + am1) + (am2 + am3) + s_lm[k];
        score += Vr[k] * tanhf(am);
    }

    if (s < SS && mask[b * SS + s]) score = -1e9f;

    // ---- 5. softmax over S within the block ----
    float v = (s < SS) ? score : -3.0e38f;
    #pragma unroll
    for (int off = 32; off > 0; off >>= 1)
        v = fmaxf(v, __shfl_down(v, off, 64));
    if (lane == 0) s_red[wv] = v;
    __syncthreads();
    float m = fmaxf(fmaxf(s_red[0], s_red[1]), fmaxf(s_red[2], s_red[3]));

    float e = (s < SS) ? expf(score - m) : 0.f;
    float sv = e;
    #pragma unroll
    for (int off = 32; off > 0; off >>= 1)
        sv += __shfl_down(sv, off, 64);
    if (lane == 0) s_red[4 + wv] = sv;
    __syncthreads();
    float tot = (s_red[4] + s_red[5]) + (s_red[6] + s_red[7]);

    // ---- 6. scatter-add (row is private to this block; duplicates within
    //         the row are possible, so atomics) ----
    if (s < SS) {
        float att = e / tot;
        int idx = item_seq[b * SS + s];
        atomicAdd(out + (size_t)b * NI + idx, att);
    }
}

extern "C" void kernel_launch(void* const* d_in, const int* in_sizes, int n_in,
                              void* d_out, int out_size, void* d_ws, size_t ws_size,
                              hipStream_t stream) {
    const float* allm   = (const float*)d_in[0];
    const float* lastm  = (const float*)d_in[1];
    const int*   iseq   = (const int*)d_in[2];
    const unsigned char* mask = (const unsigned char*)d_in[3];
    const float* Ur     = (const float*)d_in[4];
    const float* Wr     = (const float*)d_in[5];
    const float* Vr     = (const float*)d_in[6];
    const float* Vrb    = (const float*)d_in[7];
    float* out          = (float*)d_out;

    rrd_fused_kernel<<<dim3(BB), dim3(256), 0, stream>>>(
        allm, lastm, iseq, mask, Ur, Wr, Vr, Vrb, out);
}

// Round 2
// 820.354 us; speedup vs baseline: 1.1570x; 1.1570x over previous
//
#include <hip/hip_runtime.h>
#include <math.h>

#define BB 1024
#define SS 200
#define HH 128
#define NI 100000

// tanh(x) = sign(x) * (1 - e^{-2|x|}) / (1 + e^{-2|x|})
__device__ __forceinline__ float fast_tanh(float x) {
    float ax = fabsf(x);
    float t = __expf(-2.0f * ax);
    float r = (1.0f - t) / (1.0f + t);
    return copysignf(r, x);
}

__global__ __launch_bounds__(256, 3)
void rrd_fused_kernel(const float* __restrict__ allm,      // [B,S,H]
                      const float* __restrict__ lastm,     // [B,H]
                      const int* __restrict__ item_seq,    // [B,S]
                      const unsigned char* __restrict__ mask, // [B,S] bool
                      const float* __restrict__ Ur,        // [H,H]
                      const float* __restrict__ Wr,        // [H,H]
                      const float* __restrict__ Vr,        // [1,H]
                      const float* __restrict__ Vrb,       // [1]
                      float* __restrict__ out) {           // [B,N]
    const int b = blockIdx.x;
    const int tid = threadIdx.x;
    const int lane = tid & 63;
    const int wv = tid >> 6;

    // ---- 1. zero this batch's output row (N = 25000 float4 exactly) ----
    float4* orow = reinterpret_cast<float4*>(out + (size_t)b * NI);
    const float4 z4 = make_float4(0.f, 0.f, 0.f, 0.f);
    for (int i = tid; i < NI / 4; i += 256) orow[i] = z4;

    __shared__ float s_last[HH];
    __shared__ float s_lm[HH];
    __shared__ float s_vr[HH];
    __shared__ float s_red[8];

    // ---- 2. lm[k] = sum_h last[b,h] * Wr[k,h]; stage Vr too ----
    if (tid < HH) s_last[tid] = lastm[b * HH + tid];
    if (tid >= 128 && tid < 128 + HH) s_vr[tid - 128] = Vr[tid - 128];
    __syncthreads();
    if (tid < HH) {
        const float4* wrow = reinterpret_cast<const float4*>(Wr + tid * HH);
        float4 acc = make_float4(0.f, 0.f, 0.f, 0.f);
        #pragma unroll
        for (int i = 0; i < HH / 4; ++i) {
            float4 w = wrow[i];
            acc.x += s_last[4 * i]     * w.x;
            acc.y += s_last[4 * i + 1] * w.y;
            acc.z += s_last[4 * i + 2] * w.z;
            acc.w += s_last[4 * i + 3] * w.w;
        }
        s_lm[tid] = (acc.x + acc.y) + (acc.z + acc.w);
    }
    __syncthreads();

    // ---- 3. load this thread's A row into registers (32 x float4) ----
    const int s = tid;  // one s per thread; s >= SS lanes compute garbage, masked later
    float4 a[HH / 4];
    {
        const float4* arow = reinterpret_cast<const float4*>(
            allm + ((size_t)b * SS + (s < SS ? s : 0)) * HH);
        #pragma unroll
        for (int i = 0; i < HH / 4; ++i) a[i] = arow[i];
    }

    // ---- 4. score[s] = Vrb + sum_k Vr[k] * tanh(am[s,k] + lm[k]) ----
    float score = Vrb[0];
    #pragma unroll 2
    for (int k = 0; k < HH; ++k) {
        const float4* u4 = reinterpret_cast<const float4*>(Ur + (size_t)k * HH);
        float4 acc0 = make_float4(0.f, 0.f, 0.f, 0.f);
        float4 acc1 = make_float4(0.f, 0.f, 0.f, 0.f);
        #pragma unroll
        for (int i = 0; i < HH / 4; i += 2) {
            float4 u0 = u4[i];
            float4 u1 = u4[i + 1];
            acc0.x += a[i].x * u0.x;
            acc0.y += a[i].y * u0.y;
            acc0.z += a[i].z * u0.z;
            acc0.w += a[i].w * u0.w;
            acc1.x += a[i + 1].x * u1.x;
            acc1.y += a[i + 1].y * u1.y;
            acc1.z += a[i + 1].z * u1.z;
            acc1.w += a[i + 1].w * u1.w;
        }
        float am = ((acc0.x + acc0.y) + (acc0.z + acc0.w)) +
                   ((acc1.x + acc1.y) + (acc1.z + acc1.w)) + s_lm[k];
        score += s_vr[k] * fast_tanh(am);
    }

    if (s < SS && mask[b * SS + s]) score = -1e9f;

    // ---- 5. softmax over S within the block ----
    float v = (s < SS) ? score : -3.0e38f;
    #pragma unroll
    for (int off = 32; off > 0; off >>= 1)
        v = fmaxf(v, __shfl_down(v, off, 64));
    if (lane == 0) s_red[wv] = v;
    __syncthreads();
    float m = fmaxf(fmaxf(s_red[0], s_red[1]), fmaxf(s_red[2], s_red[3]));

    float e = (s < SS) ? __expf(score - m) : 0.f;
    float sv = e;
    #pragma unroll
    for (int off = 32; off > 0; off >>= 1)
        sv += __shfl_down(sv, off, 64);
    if (lane == 0) s_red[4 + wv] = sv;
    __syncthreads();
    float tot = (s_red[4] + s_red[5]) + (s_red[6] + s_red[7]);

    // ---- 6. scatter-add (row private to this block; in-row duplicates need atomics) ----
    if (s < SS) {
        float att = e / tot;
        int idx = item_seq[b * SS + s];
        atomicAdd(out + (size_t)b * NI + idx, att);
    }
}

extern "C" void kernel_launch(void* const* d_in, const int* in_sizes, int n_in,
                              void* d_out, int out_size, void* d_ws, size_t ws_size,
                              hipStream_t stream) {
    const float* allm   = (const float*)d_in[0];
    const float* lastm  = (const float*)d_in[1];
    const int*   iseq   = (const int*)d_in[2];
    const unsigned char* mask = (const unsigned char*)d_in[3];
    const float* Ur     = (const float*)d_in[4];
    const float* Wr     = (const float*)d_in[5];
    const float* Vr     = (const float*)d_in[6];
    const float* Vrb    = (const float*)d_in[7];
    float* out          = (float*)d_out;

    rrd_fused_kernel<<<dim3(BB), dim3(256), 0, stream>>>(
        allm, lastm, iseq, mask, Ur, Wr, Vr, Vrb, out);
}

// Round 3
// 674.706 us; speedup vs baseline: 1.4068x; 1.2159x over previous
//
#include <hip/hip_runtime.h>
#include <math.h>

#define BB 1024
#define SS 200
#define HH 128
#define NI 100000

// tanh(x) = sign(x) * (1 - e^{-2|x|}) / (1 + e^{-2|x|})
__device__ __forceinline__ float fast_tanh(float x) {
    float ax = fabsf(x);
    float t = __expf(-2.0f * ax);
    float r = (1.0f - t) / (1.0f + t);
    return copysignf(r, x);
}

// 32 individually-named float4 registers for the A row (NO array -> no scratch)
#define A_DECL(i) float4 A##i;
#define A_LOAD(i) A##i = arow[i];
#define FOR32(M) \
    M(0)  M(1)  M(2)  M(3)  M(4)  M(5)  M(6)  M(7)  \
    M(8)  M(9)  M(10) M(11) M(12) M(13) M(14) M(15) \
    M(16) M(17) M(18) M(19) M(20) M(21) M(22) M(23) \
    M(24) M(25) M(26) M(27) M(28) M(29) M(30) M(31)

// one float4 FMA step: c += A_i * u4[i]
#define KSTEP(i, c) { float4 uu = u4[i]; \
    c.x = fmaf(A##i.x, uu.x, c.x); \
    c.y = fmaf(A##i.y, uu.y, c.y); \
    c.z = fmaf(A##i.z, uu.z, c.z); \
    c.w = fmaf(A##i.w, uu.w, c.w); }

__global__ __launch_bounds__(256, 2)
void rrd_fused_kernel(const float* __restrict__ allm,      // [B,S,H]
                      const float* __restrict__ lastm,     // [B,H]
                      const int* __restrict__ item_seq,    // [B,S]
                      const unsigned char* __restrict__ mask, // [B,S] bool
                      const float* __restrict__ Ur,        // [H,H]
                      const float* __restrict__ Wr,        // [H,H]
                      const float* __restrict__ Vr,        // [1,H]
                      const float* __restrict__ Vrb,       // [1]
                      float* __restrict__ out) {           // [B,N]
    const int b = blockIdx.x;
    const int tid = threadIdx.x;
    const int lane = tid & 63;
    const int wv = tid >> 6;
    const int s = tid;   // one seq position per thread; s >= SS lanes are helpers

    __shared__ float s_ur[HH * HH];   // 64 KB: whole Ur, broadcast-read in k-loop
    __shared__ float s_last[HH];
    __shared__ float s_lm[HH];
    __shared__ float s_vr[HH];
    __shared__ float s_red[8];

    // ---- 1. issue A-row loads FIRST (oldest vmem ops -> usable before
    //         the fill stores drain) ----
    const float4* arow = reinterpret_cast<const float4*>(
        allm + ((size_t)b * SS + (s < SS ? s : 0)) * HH);
    FOR32(A_DECL)
    FOR32(A_LOAD)

    // ---- 2. stage Ur into LDS (coalesced, 16 float4 per thread) ----
    {
        const float4* ug = reinterpret_cast<const float4*>(Ur);
        float4* ul = reinterpret_cast<float4*>(s_ur);
        #pragma unroll
        for (int j = 0; j < (HH * HH / 4) / 256; ++j)
            ul[tid + j * 256] = ug[tid + j * 256];
    }
    if (tid < HH) s_last[tid] = lastm[b * HH + tid];
    if (tid >= 128) s_vr[tid - 128] = Vr[tid - 128];
    __syncthreads();

    // ---- 3. lm[k] = sum_h last[b,h] * Wr[k,h] ----
    if (tid < HH) {
        const float4* wrow = reinterpret_cast<const float4*>(Wr + tid * HH);
        const float4* lrow = reinterpret_cast<const float4*>(s_last);
        float4 acc = make_float4(0.f, 0.f, 0.f, 0.f);
        #pragma unroll
        for (int i = 0; i < HH / 4; ++i) {
            float4 w = wrow[i];
            float4 l = lrow[i];
            acc.x = fmaf(l.x, w.x, acc.x);
            acc.y = fmaf(l.y, w.y, acc.y);
            acc.z = fmaf(l.z, w.z, acc.z);
            acc.w = fmaf(l.w, w.w, acc.w);
        }
        s_lm[tid] = (acc.x + acc.y) + (acc.z + acc.w);
    }
    __syncthreads();

    // ---- 4. zero this batch's output row (stores are younger than all loads
    //         above; they retire during the k-loop, drained at softmax barrier)
    {
        float4* orow = reinterpret_cast<float4*>(out + (size_t)b * NI);
        const float4 z4 = make_float4(0.f, 0.f, 0.f, 0.f);
        for (int i = tid; i < NI / 4; i += 256) orow[i] = z4;
    }

    // ---- 5. score[s] = Vrb + sum_k Vr[k] * tanh(dot(A[s,:], Ur[k,:]) + lm[k])
    float score = Vrb[0];
    for (int k = 0; k < HH; ++k) {
        const float4* u4 = reinterpret_cast<const float4*>(s_ur + k * HH);
        float4 c0 = make_float4(0.f, 0.f, 0.f, 0.f);
        float4 c1 = c0, c2 = c0, c3 = c0;
        KSTEP(0,  c0) KSTEP(1,  c1) KSTEP(2,  c2) KSTEP(3,  c3)
        KSTEP(4,  c0) KSTEP(5,  c1) KSTEP(6,  c2) KSTEP(7,  c3)
        KSTEP(8,  c0) KSTEP(9,  c1) KSTEP(10, c2) KSTEP(11, c3)
        KSTEP(12, c0) KSTEP(13, c1) KSTEP(14, c2) KSTEP(15, c3)
        KSTEP(16, c0) KSTEP(17, c1) KSTEP(18, c2) KSTEP(19, c3)
        KSTEP(20, c0) KSTEP(21, c1) KSTEP(22, c2) KSTEP(23, c3)
        KSTEP(24, c0) KSTEP(25, c1) KSTEP(26, c2) KSTEP(27, c3)
        KSTEP(28, c0) KSTEP(29, c1) KSTEP(30, c2) KSTEP(31, c3)
        float r0 = (c0.x + c0.y) + (c0.z + c0.w);
        float r1 = (c1.x + c1.y) + (c1.z + c1.w);
        float r2 = (c2.x + c2.y) + (c2.z + c2.w);
        float r3 = (c3.x + c3.y) + (c3.z + c3.w);
        float am = ((r0 + r1) + (r2 + r3)) + s_lm[k];
        score = fmaf(s_vr[k], fast_tanh(am), score);
    }

    if (s < SS && mask[b * SS + s]) score = -1e9f;

    // ---- 6. softmax over S within the block ----
    float v = (s < SS) ? score : -3.0e38f;
    #pragma unroll
    for (int off = 32; off > 0; off >>= 1)
        v = fmaxf(v, __shfl_down(v, off, 64));
    if (lane == 0) s_red[wv] = v;
    __syncthreads();   // also drains the fill stores (long retired by now)
    float m = fmaxf(fmaxf(s_red[0], s_red[1]), fmaxf(s_red[2], s_red[3]));

    float e = (s < SS) ? __expf(score - m) : 0.f;
    float sv = e;
    #pragma unroll
    for (int off = 32; off > 0; off >>= 1)
        sv += __shfl_down(sv, off, 64);
    if (lane == 0) s_red[4 + wv] = sv;
    __syncthreads();
    float tot = (s_red[4] + s_red[5]) + (s_red[6] + s_red[7]);

    // ---- 7. scatter-add (row private to block; in-row duplicate ids -> atomics)
    if (s < SS) {
        float att = e / tot;
        int idx = item_seq[b * SS + s];
        atomicAdd(out + (size_t)b * NI + idx, att);
    }
}

extern "C" void kernel_launch(void* const* d_in, const int* in_sizes, int n_in,
                              void* d_out, int out_size, void* d_ws, size_t ws_size,
                              hipStream_t stream) {
    const float* allm   = (const float*)d_in[0];
    const float* lastm  = (const float*)d_in[1];
    const int*   iseq   = (const int*)d_in[2];
    const unsigned char* mask = (const unsigned char*)d_in[3];
    const float* Ur     = (const float*)d_in[4];
    const float* Wr     = (const float*)d_in[5];
    const float* Vr     = (const float*)d_in[6];
    const float* Vrb    = (const float*)d_in[7];
    float* out          = (float*)d_out;

    rrd_fused_kernel<<<dim3(BB), dim3(256), 0, stream>>>(
        allm, lastm, iseq, mask, Ur, Wr, Vr, Vrb, out);
}